// Round 5
// baseline (616.756 us; speedup 1.0000x reference)
//
#include <hip/hip_runtime.h>
#include <hip/hip_bf16.h>

#define LNUM 4
#define DIM  512
#define SS   256

typedef unsigned short ushort_t;
typedef __attribute__((ext_vector_type(8))) short bf16x8;
typedef __attribute__((ext_vector_type(4))) float f32x4;
typedef __attribute__((ext_vector_type(8))) unsigned short u16x8;

#define VWAIT(n) asm volatile("s_waitcnt vmcnt(" #n ")" ::: "memory")
__device__ __forceinline__ void bar() { __builtin_amdgcn_s_barrier(); }

__device__ __forceinline__ ushort_t f2b(float f) {
  union { float f; unsigned u; } x; x.f = f;
  unsigned r = x.u + 0x7FFFu + ((x.u >> 16) & 1u);
  return (ushort_t)(r >> 16);
}

__device__ __forceinline__ void gload16(const void* g, void* s) {
  __builtin_amdgcn_global_load_lds((const __attribute__((address_space(1))) void*)g,
                                   (__attribute__((address_space(3))) void*)s, 16, 0, 0);
}

// ---------------------------------------------------------------------------
// C = A * B^T, 3-buffer depth-2 pipeline, counted vmcnt, raw barriers.
// EPI 0: outB = bf16(acc + bias) [relu opt]
// EPI 2: outF[kz partial] = acc + bias(kz==0)   (plain fp32 store)
// EPI 3: fused QKV routing; V segment repacked via LDS -> vT coalesced
// ---------------------------------------------------------------------------
template<int TM, int TN, int EPI>
__global__ __launch_bounds__(256, 2)
void gemm_bt(const ushort_t* __restrict__ A, const ushort_t* __restrict__ B,
             const float* __restrict__ bias, const float* __restrict__ bias2,
             const float* __restrict__ bias3,
             ushort_t* __restrict__ outB, ushort_t* __restrict__ outB2,
             ushort_t* __restrict__ outB3, float* __restrict__ outF,
             int K, int lda, int ldb, int ldc, int nkz, int relu)
{
  constexpr int CA = TM / 32, CB = TN / 32, SN = CA + CB;
  constexpr int WM = TM / 32, WN = TN / 32;
  __shared__ ushort_t As[3 * TM * 64];
  __shared__ ushort_t Bs[3 * TN * 64];
  const int tid = threadIdx.x, lane = tid & 63, wid = tid >> 6;
  const int wm = wid >> 1, wn = wid & 1;
  const int kz = blockIdx.z, Kz = K / nkz, k0 = kz * Kz, nt = Kz >> 6;

  const ushort_t* Ab = A + (long)blockIdx.y * TM * lda + k0;
  const ushort_t* Bb = B + (long)blockIdx.x * TN * ldb + k0;

  const ushort_t* srcA[CA]; ushort_t* ldsA[CA];
  const ushort_t* srcB[CB]; ushort_t* ldsB[CB];
#pragma unroll
  for (int c = 0; c < CA; ++c) {
    int off = c * 4096 + tid * 16;
    int row = off >> 7;
    int scol = ((off & 127) ^ ((row & 7) << 4)) >> 1;
    srcA[c] = Ab + (long)row * lda + scol;
    ldsA[c] = As + c * 2048 + wid * 512;
  }
#pragma unroll
  for (int c = 0; c < CB; ++c) {
    int off = c * 4096 + tid * 16;
    int row = off >> 7;
    int scol = ((off & 127) ^ ((row & 7) << 4)) >> 1;
    srcB[c] = Bb + (long)row * ldb + scol;
    ldsB[c] = Bs + c * 2048 + wid * 512;
  }

  f32x4 acc[WM][WN] = {};

  auto STAGE = [&](int buf, int t) {
#pragma unroll
    for (int c = 0; c < CA; ++c) gload16(srcA[c] + t * 64, ldsA[c] + buf * TM * 64);
#pragma unroll
    for (int c = 0; c < CB; ++c) gload16(srcB[c] + t * 64, ldsB[c] + buf * TN * 64);
  };

  STAGE(0, 0);
  STAGE(1, 1);
  for (int t = 0; t < nt; ++t) {
    if (t < nt - 1) { if constexpr (SN == 6) VWAIT(6); else VWAIT(4); }
    else VWAIT(0);
    bar();
    if (t + 2 < nt) STAGE((t + 2) % 3, t + 2);
    const int buf = t % 3;
#pragma unroll
    for (int ks = 0; ks < 2; ++ks) {
      const int kb = ks * 64 + ((lane >> 4) << 4);
      bf16x8 af[WM], bfr[WN];
#pragma unroll
      for (int f = 0; f < WM; ++f) {
        int ra = wm * (TM / 2) + f * 16 + (lane & 15);
        af[f] = *(const bf16x8*)((const char*)As + buf * TM * 128 + ra * 128 + (kb ^ ((ra & 7) << 4)));
      }
#pragma unroll
      for (int g = 0; g < WN; ++g) {
        int rb = wn * (TN / 2) + g * 16 + (lane & 15);
        bfr[g] = *(const bf16x8*)((const char*)Bs + buf * TN * 128 + rb * 128 + (kb ^ ((rb & 7) << 4)));
      }
      __builtin_amdgcn_s_setprio(1);
#pragma unroll
      for (int i = 0; i < WM; ++i)
#pragma unroll
        for (int j = 0; j < WN; ++j)
          acc[i][j] = __builtin_amdgcn_mfma_f32_16x16x32_bf16(af[i], bfr[j], acc[i][j], 0, 0, 0);
      __builtin_amdgcn_s_setprio(0);
    }
  }

  const int row0 = blockIdx.y * TM + wm * (TM / 2) + ((lane >> 4) << 2);
  int col0 = blockIdx.x * TN + wn * (TN / 2) + (lane & 15);
  const float* bsel = bias;
  ushort_t* osel = outB;
  int seg = 0;
  if (EPI == 3) {
    seg = (blockIdx.x * TN) >> 11;
    if (seg == 1) { bsel = bias2; osel = outB2; }
    else if (seg == 2) { bsel = bias3; }
    col0 -= seg * 2048;
  }

  if (EPI == 3 && seg == 2) {
    // V segment: repack 128(row) x 64(col) tile via LDS, write vT[bh][dk][s]
    ushort_t* Vt = As;              // reuse staging LDS (padded stride 136)
    bar();                          // all waves done reading As
#pragma unroll
    for (int i = 0; i < WM; ++i)
#pragma unroll
      for (int j = 0; j < WN; ++j) {
        const int colL = wn * (TN / 2) + j * 16 + (lane & 15);
        const float bv = bsel[(col0 + j * 16) & 2047];
#pragma unroll
        for (int r = 0; r < 4; ++r) {
          const int rowL = wm * (TM / 2) + i * 16 + ((lane >> 4) << 2) + r;
          Vt[colL * 136 + rowL] = f2b(acc[i][j][r] + bv);
        }
      }
    bar();
    const int colvBase = blockIdx.x * TN - 4096;         // within V's 2048 cols
    const int h = colvBase >> 8, dk0 = colvBase & 255;
    const int rowBase = blockIdx.y * TM;
    const int bh = ((rowBase >> 8) << 3) + h;
    const int s0 = rowBase & 255;
    const int dkl = tid >> 2, scc = (tid & 3) * 32;
    ushort_t* dst = outB3 + ((long)bh << 16) + (long)(dk0 + dkl) * 256 + s0 + scc;
#pragma unroll
    for (int m = 0; m < 4; ++m)
      *(u16x8*)(dst + m * 8) = *(const u16x8*)(Vt + dkl * 136 + scc + m * 8);
    return;
  }

#pragma unroll
  for (int i = 0; i < WM; ++i) {
#pragma unroll
    for (int j = 0; j < WN; ++j) {
      const int col = col0 + j * 16;
      float bv;
      if (EPI == 2) bv = (kz == 0) ? bias[col] : 0.f;
      else          bv = bsel[col];
#pragma unroll
      for (int r = 0; r < 4; ++r) {
        const int row = row0 + i * 16 + r;
        float v = acc[i][j][r] + bv;
        if (EPI == 2) {
          outF[(long)kz * 1048576 + (long)row * ldc + col] = v;
        } else {
          if (relu) v = fmaxf(v, 0.f);
          osel[(long)row * ldc + col] = f2b(v);
        }
      }
    }
  }
}

// ---------------------------------------------------------------------------
// Attention: one wave (64 threads) per (16-row q-tile, b*8+h). No barriers.
// Q/S/O in registers; K,V fragments loaded straight from L2; P and the O
// repack make one 8KB swizzled-LDS round trip each.
// ---------------------------------------------------------------------------
__global__ __launch_bounds__(64, 2)
void attn_k(const ushort_t* __restrict__ qb, const ushort_t* __restrict__ kbf,
            const ushort_t* __restrict__ vT, const int* __restrict__ attnm,
            ushort_t* __restrict__ ao)
{
  __shared__ ushort_t Ps[16 * 256];          // 8KB, XOR-swizzled rows
  const int qt = blockIdx.x, bh = blockIdx.y, b = bh >> 3, h = bh & 7;
  const int lane = threadIdx.x;
  const int l15 = lane & 15, l4 = lane >> 4;
  const int q0 = qt * 16;

  // pack key mask into bits (bit kt = mask of key kt*16+l15)
  unsigned mbits = 0;
#pragma unroll
  for (int kt = 0; kt < 16; ++kt)
    mbits |= (attnm[b * 256 + kt * 16 + l15] != 0 ? 1u : 0u) << kt;

  // Q fragments: row = q0+l15, k = ks*32 + l4*8
  const ushort_t* qp = qb + (long)(b * 256 + q0 + l15) * 2048 + h * 256 + l4 * 8;
  bf16x8 qf[8];
#pragma unroll
  for (int ks = 0; ks < 8; ++ks) qf[ks] = *(const bf16x8*)(qp + ks * 32);

  // S = Q K^T
  f32x4 sacc[16] = {};
  const ushort_t* kp = kbf + (long)(b * 256 + l15) * 2048 + h * 256 + l4 * 8;
#pragma unroll 2
  for (int kt = 0; kt < 16; ++kt) {
    bf16x8 kf[8];
#pragma unroll
    for (int ks = 0; ks < 8; ++ks)
      kf[ks] = *(const bf16x8*)(kp + (long)kt * 16 * 2048 + ks * 32);
#pragma unroll
    for (int ks = 0; ks < 8; ++ks)
      sacc[kt] = __builtin_amdgcn_mfma_f32_16x16x32_bf16(qf[ks], kf[ks], sacc[kt], 0, 0, 0);
  }

  // softmax over 256 keys; lane holds keys kt*16+l15 for q-rows l4*4+r
  float mr[4] = {-3e38f, -3e38f, -3e38f, -3e38f}, sr[4] = {};
#pragma unroll
  for (int kt = 0; kt < 16; ++kt) {
    const bool mk = (mbits >> kt) & 1;
#pragma unroll
    for (int r = 0; r < 4; ++r) {
      float s = mk ? -1e9f : sacc[kt][r] * 0.0625f;
      sacc[kt][r] = s;
      mr[r] = fmaxf(mr[r], s);
    }
  }
#pragma unroll
  for (int o = 1; o < 16; o <<= 1)
#pragma unroll
    for (int r = 0; r < 4; ++r) mr[r] = fmaxf(mr[r], __shfl_xor(mr[r], o, 16));
#pragma unroll
  for (int kt = 0; kt < 16; ++kt)
#pragma unroll
    for (int r = 0; r < 4; ++r) {
      float e = __expf(sacc[kt][r] - mr[r]);
      sacc[kt][r] = e;
      sr[r] += e;
    }
#pragma unroll
  for (int o = 1; o < 16; o <<= 1)
#pragma unroll
    for (int r = 0; r < 4; ++r) sr[r] += __shfl_xor(sr[r], o, 16);
#pragma unroll
  for (int r = 0; r < 4; ++r) sr[r] = 1.f / sr[r];

  // P -> LDS (swizzled): row = l4*4+r, colbyte = (kt*16+l15)*2
#pragma unroll
  for (int kt = 0; kt < 16; ++kt)
#pragma unroll
    for (int r = 0; r < 4; ++r) {
      const int row = l4 * 4 + r;
      *(ushort_t*)((char*)Ps + row * 512 + (((kt * 16 + l15) * 2) ^ ((row & 7) << 4))) =
          f2b(sacc[kt][r] * sr[r]);
    }

  // P fragments: row = l15, keybytes = ks*64 + l4*16
  bf16x8 pf[8];
#pragma unroll
  for (int ks = 0; ks < 8; ++ks)
    pf[ks] = *(const bf16x8*)((const char*)Ps + l15 * 512 + ((ks * 64 + l4 * 16) ^ ((l15 & 7) << 4)));

  // O = P V   (V^T fragments from L2: dk-row = dt*16+l15, key = ks*32+l4*8)
  f32x4 oacc[16] = {};
  const ushort_t* vp = vT + ((long)bh << 16) + (long)l15 * 256 + l4 * 8;
#pragma unroll 2
  for (int dt = 0; dt < 16; ++dt) {
    bf16x8 vf[8];
#pragma unroll
    for (int ks = 0; ks < 8; ++ks)
      vf[ks] = *(const bf16x8*)(vp + dt * 16 * 256 + ks * 32);
#pragma unroll
    for (int ks = 0; ks < 8; ++ks)
      oacc[dt] = __builtin_amdgcn_mfma_f32_16x16x32_bf16(pf[ks], vf[ks], oacc[dt], 0, 0, 0);
  }

  // O -> LDS (reuse Ps, swizzled) -> coalesced 16B stores
#pragma unroll
  for (int dt = 0; dt < 16; ++dt)
#pragma unroll
    for (int r = 0; r < 4; ++r) {
      const int row = l4 * 4 + r;
      *(ushort_t*)((char*)Ps + row * 512 + (((dt * 16 + l15) * 2) ^ ((row & 7) << 4))) =
          f2b(oacc[dt][r]);
    }
  ushort_t* dst = ao + (long)(b * 256 + q0 + l15) * 2048 + h * 256 + l4 * 64;
#pragma unroll
  for (int m = 0; m < 8; ++m) {
    const int cbyte = l4 * 128 + m * 16;
    u16x8 v = *(const u16x8*)((const char*)Ps + l15 * 512 + (cbyte ^ ((l15 & 7) << 4)));
    *(u16x8*)(dst + m * 8) = v;
  }
}

// x = data*sqrt(D) + pe + seg_emb[view_idx*S]
__global__ __launch_bounds__(256)
void build_x(const float* __restrict__ data, const float* __restrict__ seg,
             const int* __restrict__ viewp, float* __restrict__ x)
{
  int i = blockIdx.x * 256 + threadIdx.x;
  int d = i & 511;
  int s = (i >> 9) & 255;
  float ang = (float)s * exp2f((float)d * -0.03125f);
  float pe = (d & 1) ? cosf(ang) : sinf(ang);
  int vrow = viewp[0] * SS;
  x[i] = data[i] * 22.627416997969522f + pe + seg[vrow * DIM + d];
}

// LayerNorm with optional fused residual: x += sum(parts[0..np)), write back,
// then normalize (unbiased var, eps on std). outB: bf16 out; outF: fp32 out.
__global__ __launch_bounds__(256)
void lnorm_k(const float* __restrict__ x, const float* __restrict__ parts, int np,
             float* __restrict__ xout,
             const float* __restrict__ alpha, const float* __restrict__ beta,
             ushort_t* __restrict__ outB, float* __restrict__ outF)
{
  const int row = blockIdx.x, tid = threadIdx.x;
  const long base = (long)row * DIM;
  float2 v = ((const float2*)(x + base))[tid];
  if (np) {
    for (int p = 0; p < np; ++p) {
      float2 a = ((const float2*)(parts + (long)p * 1048576 + base))[tid];
      v.x += a.x; v.y += a.y;
    }
    ((float2*)(xout + base))[tid] = v;
  }
  float s = v.x + v.y;
#pragma unroll
  for (int o = 32; o; o >>= 1) s += __shfl_xor(s, o, 64);
  __shared__ float rs[4], rq[4];
  if ((tid & 63) == 0) rs[tid >> 6] = s;
  __syncthreads();
  const float mu = (rs[0] + rs[1] + rs[2] + rs[3]) * (1.f / 512.f);
  const float dx = v.x - mu, dy = v.y - mu;
  float q = dx * dx + dy * dy;
#pragma unroll
  for (int o = 32; o; o >>= 1) q += __shfl_xor(q, o, 64);
  if ((tid & 63) == 0) rq[tid >> 6] = q;
  __syncthreads();
  const float var = (rq[0] + rq[1] + rq[2] + rq[3]) * (1.f / 511.f);
  const float rstd = 1.f / (sqrtf(var) + 1e-6f);
  const int d0 = tid * 2;
  const float o0 = alpha[d0] * dx * rstd + beta[d0];
  const float o1 = alpha[d0 + 1] * dy * rstd + beta[d0 + 1];
  if (outB) { outB[base + d0] = f2b(o0); outB[base + d0 + 1] = f2b(o1); }
  else      { outF[base + d0] = o0;      outF[base + d0 + 1] = o1; }
}

// fp32 [R,C] -> bf16 [C,R], per-z with output z-stride (elements)
__global__ __launch_bounds__(256)
void wtrans(const float* __restrict__ in, ushort_t* __restrict__ out,
            int R, int C, long ozs)
{
  __shared__ float t[32][33];
  const int z = blockIdx.z;
  const long zi = (long)z * R * C, zo = (long)z * ozs;
  const int c0 = blockIdx.x * 32, r0 = blockIdx.y * 32;
  const int tx = threadIdx.x & 31, ty = threadIdx.x >> 5;
#pragma unroll
  for (int i = 0; i < 4; ++i) t[ty + i * 8][tx] = in[zi + (long)(r0 + ty + i * 8) * C + c0 + tx];
  __syncthreads();
#pragma unroll
  for (int i = 0; i < 4; ++i) out[zo + (long)(c0 + ty + i * 8) * R + r0 + tx] = f2b(t[tx][ty + i * 8]);
}

extern "C" void kernel_launch(void* const* d_in, const int* in_sizes, int n_in,
                              void* d_out, int out_size, void* d_ws, size_t ws_size,
                              hipStream_t stream)
{
  const float* data  = (const float*)d_in[0];
  const int*   attnm = (const int*)d_in[1];
  const int*   viewp = (const int*)d_in[2];
  const float* seg   = (const float*)d_in[3];
  const float* Wq    = (const float*)d_in[4];
  const float* bq    = (const float*)d_in[5];
  const float* Wk    = (const float*)d_in[6];
  const float* bk    = (const float*)d_in[7];
  const float* Wv    = (const float*)d_in[8];
  const float* bv    = (const float*)d_in[9];
  const float* Wo    = (const float*)d_in[10];
  const float* bo    = (const float*)d_in[11];
  const float* W1    = (const float*)d_in[12];
  const float* b1    = (const float*)d_in[13];
  const float* W2    = (const float*)d_in[14];
  const float* b2    = (const float*)d_in[15];
  const float* al1   = (const float*)d_in[16];
  const float* be1   = (const float*)d_in[17];
  const float* al2   = (const float*)d_in[18];
  const float* be2   = (const float*)d_in[19];
  const float* alf   = (const float*)d_in[20];
  const float* bef   = (const float*)d_in[21];

  char* w = (char*)d_ws;
  const size_t MB = 1024 * 1024;
  ushort_t* qkvW = (ushort_t*)(w + 0 * MB);   // [L][6144][512] bf16
  ushort_t* WoT  = (ushort_t*)(w + 24 * MB);  // [L][512][2048]
  ushort_t* W1T  = (ushort_t*)(w + 32 * MB);  // [L][2048][512]
  ushort_t* W2T  = (ushort_t*)(w + 40 * MB);  // [L][512][2048]
  float*    x    = (float*)   (w + 48 * MB);  // [2048][512] fp32
  ushort_t* x2   = (ushort_t*)(w + 52 * MB);  // [2048][512] bf16
  ushort_t* qb   = (ushort_t*)(w + 54 * MB);  // [2048][2048] bf16
  ushort_t* kbf  = (ushort_t*)(w + 62 * MB);
  ushort_t* vT   = (ushort_t*)(w + 70 * MB);  // [64][256][256]
  ushort_t* ao   = (ushort_t*)(w + 78 * MB);  // [2048][2048]
  ushort_t* ffh  = (ushort_t*)(w + 86 * MB);  // [2048][2048]
  float*    parts= (float*)   (w + 94 * MB);  // 4 x [2048][512] fp32 (94..110MB)

  dim3 blk(256);
  const long QKV_L = 6144L * 512;
  wtrans<<<dim3(64, 16, 4), blk, 0, stream>>>(Wq, qkvW + 0 * 2048 * 512, 512, 2048, QKV_L);
  wtrans<<<dim3(64, 16, 4), blk, 0, stream>>>(Wk, qkvW + 1 * 2048 * 512, 512, 2048, QKV_L);
  wtrans<<<dim3(64, 16, 4), blk, 0, stream>>>(Wv, qkvW + 2 * 2048 * 512, 512, 2048, QKV_L);
  wtrans<<<dim3(16, 64, 4), blk, 0, stream>>>(Wo, WoT, 2048, 512, 512L * 2048);
  wtrans<<<dim3(64, 16, 4), blk, 0, stream>>>(W1, W1T, 512, 2048, 2048L * 512);
  wtrans<<<dim3(16, 64, 4), blk, 0, stream>>>(W2, W2T, 2048, 512, 512L * 2048);
  build_x<<<4096, blk, 0, stream>>>(data, seg, viewp, x);

  for (int i = 0; i < LNUM; ++i) {
    if (i == 0)
      lnorm_k<<<2048, blk, 0, stream>>>(x, nullptr, 0, nullptr, al1, be1, x2, nullptr);
    // fused QKV: [2048,512] x [6144,512]^T ; V repacked via LDS to vT
    gemm_bt<128, 64, 3><<<dim3(96, 16, 1), blk, 0, stream>>>(
        x2, qkvW + (long)i * QKV_L, bq + i * 2048, bk + i * 2048, bv + i * 2048,
        qb, kbf, vT, nullptr, 512, 512, 512, 2048, 1, 0);
    attn_k<<<dim3(16, 64), dim3(64), 0, stream>>>(qb, kbf, vT, attnm, ao);
    // Wo: [2048,2048] x [512,2048]^T, split-K=4 -> parts
    gemm_bt<64, 64, 2><<<dim3(8, 32, 4), blk, 0, stream>>>(
        ao, WoT + (long)i * 512 * 2048, bo + i * 512, nullptr, nullptr,
        nullptr, nullptr, nullptr, parts, 2048, 2048, 2048, 512, 4, 0);
    lnorm_k<<<2048, blk, 0, stream>>>(x, parts, 4, x, al2 + i * 512, be2 + i * 512, x2, nullptr);
    // FF1: [2048,512] x [2048,512]^T, relu
    gemm_bt<128, 64, 0><<<dim3(32, 16, 1), blk, 0, stream>>>(
        x2, W1T + (long)i * 2048 * 512, b1 + i * 2048, nullptr, nullptr,
        ffh, nullptr, nullptr, nullptr, 512, 512, 512, 2048, 1, 1);
    // FF2: [2048,2048] x [512,2048]^T, split-K=4 -> parts
    gemm_bt<64, 64, 2><<<dim3(8, 32, 4), blk, 0, stream>>>(
        ffh, W2T + (long)i * 512 * 2048, b2 + i * 512, nullptr, nullptr,
        nullptr, nullptr, nullptr, parts, 2048, 2048, 2048, 512, 4, 0);
    if (i < LNUM - 1)
      lnorm_k<<<2048, blk, 0, stream>>>(x, parts, 4, x, al1 + (i + 1) * 512, be1 + (i + 1) * 512, x2, nullptr);
    else
      lnorm_k<<<2048, blk, 0, stream>>>(x, parts, 4, x, alf, bef, nullptr, (float*)d_out);
  }
}

// Round 6
// 603.189 us; speedup vs baseline: 1.0225x; 1.0225x over previous
//
#include <hip/hip_runtime.h>
#include <hip/hip_bf16.h>

#define LNUM 4
#define DIM  512
#define SS   256

typedef unsigned short ushort_t;
typedef __attribute__((ext_vector_type(8))) short bf16x8;
typedef __attribute__((ext_vector_type(4))) float f32x4;
typedef __attribute__((ext_vector_type(8))) unsigned short u16x8;

#define VWAIT(n) asm volatile("s_waitcnt vmcnt(" #n ")" ::: "memory")
__device__ __forceinline__ void bar() { __builtin_amdgcn_s_barrier(); }

__device__ __forceinline__ ushort_t f2b(float f) {
  union { float f; unsigned u; } x; x.f = f;
  unsigned r = x.u + 0x7FFFu + ((x.u >> 16) & 1u);
  return (ushort_t)(r >> 16);
}

__device__ __forceinline__ void gload16(const void* g, void* s) {
  __builtin_amdgcn_global_load_lds((const __attribute__((address_space(1))) void*)g,
                                   (__attribute__((address_space(3))) void*)s, 16, 0, 0);
}

// ---------------------------------------------------------------------------
// C = A * B^T, 3-buffer depth-2 pipeline, counted vmcnt, raw barriers.
// EPI 0: outB = bf16(acc + bias) [relu opt]
// EPI 2: outF[kz partial] = acc + bias(kz==0)   (plain fp32 store)
// EPI 3: fused QKV routing; V segment repacked via LDS -> vT coalesced
// ---------------------------------------------------------------------------
template<int TM, int TN, int EPI>
__global__ __launch_bounds__(256, 2)
void gemm_bt(const ushort_t* __restrict__ A, const ushort_t* __restrict__ B,
             const float* __restrict__ bias, const float* __restrict__ bias2,
             const float* __restrict__ bias3,
             ushort_t* __restrict__ outB, ushort_t* __restrict__ outB2,
             ushort_t* __restrict__ outB3, float* __restrict__ outF,
             int K, int lda, int ldb, int ldc, int nkz, int relu)
{
  constexpr int CA = TM / 32, CB = TN / 32, SN = CA + CB;
  constexpr int WM = TM / 32, WN = TN / 32;
  __shared__ ushort_t As[3 * TM * 64];
  __shared__ ushort_t Bs[3 * TN * 64];
  const int tid = threadIdx.x, lane = tid & 63, wid = tid >> 6;
  const int wm = wid >> 1, wn = wid & 1;
  const int kz = blockIdx.z, Kz = K / nkz, k0 = kz * Kz, nt = Kz >> 6;

  const ushort_t* Ab = A + (long)blockIdx.y * TM * lda + k0;
  const ushort_t* Bb = B + (long)blockIdx.x * TN * ldb + k0;

  const ushort_t* srcA[CA]; ushort_t* ldsA[CA];
  const ushort_t* srcB[CB]; ushort_t* ldsB[CB];
#pragma unroll
  for (int c = 0; c < CA; ++c) {
    int off = c * 4096 + tid * 16;
    int row = off >> 7;
    int scol = ((off & 127) ^ ((row & 7) << 4)) >> 1;
    srcA[c] = Ab + (long)row * lda + scol;
    ldsA[c] = As + c * 2048 + wid * 512;
  }
#pragma unroll
  for (int c = 0; c < CB; ++c) {
    int off = c * 4096 + tid * 16;
    int row = off >> 7;
    int scol = ((off & 127) ^ ((row & 7) << 4)) >> 1;
    srcB[c] = Bb + (long)row * ldb + scol;
    ldsB[c] = Bs + c * 2048 + wid * 512;
  }

  f32x4 acc[WM][WN] = {};

  auto STAGE = [&](int buf, int t) {
#pragma unroll
    for (int c = 0; c < CA; ++c) gload16(srcA[c] + t * 64, ldsA[c] + buf * TM * 64);
#pragma unroll
    for (int c = 0; c < CB; ++c) gload16(srcB[c] + t * 64, ldsB[c] + buf * TN * 64);
  };

  STAGE(0, 0);
  STAGE(1, 1);
  for (int t = 0; t < nt; ++t) {
    if (t < nt - 1) { if constexpr (SN == 6) VWAIT(6); else VWAIT(4); }
    else VWAIT(0);
    bar();
    if (t + 2 < nt) STAGE((t + 2) % 3, t + 2);
    const int buf = t % 3;
#pragma unroll
    for (int ks = 0; ks < 2; ++ks) {
      const int kb = ks * 64 + ((lane >> 4) << 4);
      bf16x8 af[WM], bfr[WN];
#pragma unroll
      for (int f = 0; f < WM; ++f) {
        int ra = wm * (TM / 2) + f * 16 + (lane & 15);
        af[f] = *(const bf16x8*)((const char*)As + buf * TM * 128 + ra * 128 + (kb ^ ((ra & 7) << 4)));
      }
#pragma unroll
      for (int g = 0; g < WN; ++g) {
        int rb = wn * (TN / 2) + g * 16 + (lane & 15);
        bfr[g] = *(const bf16x8*)((const char*)Bs + buf * TN * 128 + rb * 128 + (kb ^ ((rb & 7) << 4)));
      }
      __builtin_amdgcn_s_setprio(1);
#pragma unroll
      for (int i = 0; i < WM; ++i)
#pragma unroll
        for (int j = 0; j < WN; ++j)
          acc[i][j] = __builtin_amdgcn_mfma_f32_16x16x32_bf16(af[i], bfr[j], acc[i][j], 0, 0, 0);
      __builtin_amdgcn_s_setprio(0);
    }
  }

  const int row0 = blockIdx.y * TM + wm * (TM / 2) + ((lane >> 4) << 2);
  int col0 = blockIdx.x * TN + wn * (TN / 2) + (lane & 15);
  const float* bsel = bias;
  ushort_t* osel = outB;
  int seg = 0;
  if (EPI == 3) {
    seg = (blockIdx.x * TN) >> 11;
    if (seg == 1) { bsel = bias2; osel = outB2; }
    else if (seg == 2) { bsel = bias3; }
    col0 -= seg * 2048;
  }

  if (EPI == 3 && seg == 2) {
    // V segment: repack 128(row) x 64(col) tile via LDS, write vT[bh][dk][s]
    ushort_t* Vt = As;              // reuse staging LDS (padded stride 136)
    bar();                          // all waves done reading As
#pragma unroll
    for (int i = 0; i < WM; ++i)
#pragma unroll
      for (int j = 0; j < WN; ++j) {
        const int colL = wn * (TN / 2) + j * 16 + (lane & 15);
        const float bv = bsel[(col0 + j * 16) & 2047];
#pragma unroll
        for (int r = 0; r < 4; ++r) {
          const int rowL = wm * (TM / 2) + i * 16 + ((lane >> 4) << 2) + r;
          Vt[colL * 136 + rowL] = f2b(acc[i][j][r] + bv);
        }
      }
    bar();
    const int colvBase = blockIdx.x * TN - 4096;         // within V's 2048 cols
    const int h = colvBase >> 8, dk0 = colvBase & 255;
    const int rowBase = blockIdx.y * TM;
    const int bh = ((rowBase >> 8) << 3) + h;
    const int s0 = rowBase & 255;
    const int dkl = tid >> 2, scc = (tid & 3) * 32;
    ushort_t* dst = outB3 + ((long)bh << 16) + (long)(dk0 + dkl) * 256 + s0 + scc;
#pragma unroll
    for (int m = 0; m < 4; ++m)
      *(u16x8*)(dst + m * 8) = *(const u16x8*)(Vt + dkl * 136 + scc + m * 8);
    return;
  }

#pragma unroll
  for (int i = 0; i < WM; ++i) {
#pragma unroll
    for (int j = 0; j < WN; ++j) {
      const int col = col0 + j * 16;
      float bv;
      if (EPI == 2) bv = (kz == 0) ? bias[col] : 0.f;
      else          bv = bsel[col];
#pragma unroll
      for (int r = 0; r < 4; ++r) {
        const int row = row0 + i * 16 + r;
        float v = acc[i][j][r] + bv;
        if (EPI == 2) {
          outF[(long)kz * 1048576 + (long)row * ldc + col] = v;
        } else {
          if (relu) v = fmaxf(v, 0.f);
          osel[(long)row * ldc + col] = f2b(v);
        }
      }
    }
  }
}

// ---------------------------------------------------------------------------
// Attention: one wave (64 threads) per (16-row q-tile, head). XCD-aware block
// mapping keeps all 16 q-tiles of a head on one XCD (8 heads/XCD -> K/V L2-
// resident). Q/S/O in registers; K,V fragments loaded straight from L2;
// P and the O repack make one 8KB swizzled-LDS round trip each.
// ---------------------------------------------------------------------------
__global__ __launch_bounds__(64, 1)
void attn_k(const ushort_t* __restrict__ qb, const ushort_t* __restrict__ kbf,
            const ushort_t* __restrict__ vT, const int* __restrict__ attnm,
            ushort_t* __restrict__ ao)
{
  __shared__ ushort_t Ps[16 * 256];          // 8KB, XOR-swizzled rows
  const int i = blockIdx.x;
  const int xcd = i & 7, slot = i >> 3;
  const int bh = xcd + 8 * (slot >> 4);      // all 16 q-tiles of bh on one XCD
  const int qt = slot & 15;
  const int b = bh >> 3, h = bh & 7;
  const int lane = threadIdx.x;
  const int l15 = lane & 15, l4 = lane >> 4;
  const int q0 = qt * 16;

  // pack key mask into bits (bit kt = mask of key kt*16+l15)
  unsigned mbits = 0;
#pragma unroll
  for (int kt = 0; kt < 16; ++kt)
    mbits |= (attnm[b * 256 + kt * 16 + l15] != 0 ? 1u : 0u) << kt;

  // Q fragments: row = q0+l15, k = ks*32 + l4*8
  const ushort_t* qp = qb + (long)(b * 256 + q0 + l15) * 2048 + h * 256 + l4 * 8;
  bf16x8 qf[8];
#pragma unroll
  for (int ks = 0; ks < 8; ++ks) qf[ks] = *(const bf16x8*)(qp + ks * 32);

  // S = Q K^T
  f32x4 sacc[16] = {};
  const ushort_t* kp = kbf + (long)(b * 256 + l15) * 2048 + h * 256 + l4 * 8;
#pragma unroll 2
  for (int kt = 0; kt < 16; ++kt) {
    bf16x8 kf[8];
#pragma unroll
    for (int ks = 0; ks < 8; ++ks)
      kf[ks] = *(const bf16x8*)(kp + (long)kt * 16 * 2048 + ks * 32);
#pragma unroll
    for (int ks = 0; ks < 8; ++ks)
      sacc[kt] = __builtin_amdgcn_mfma_f32_16x16x32_bf16(qf[ks], kf[ks], sacc[kt], 0, 0, 0);
  }

  // softmax over 256 keys; lane holds keys kt*16+l15 for q-rows l4*4+r
  float mr[4] = {-3e38f, -3e38f, -3e38f, -3e38f}, sr[4] = {};
#pragma unroll
  for (int kt = 0; kt < 16; ++kt) {
    const bool mk = (mbits >> kt) & 1;
#pragma unroll
    for (int r = 0; r < 4; ++r) {
      float s = mk ? -1e9f : sacc[kt][r] * 0.0625f;
      sacc[kt][r] = s;
      mr[r] = fmaxf(mr[r], s);
    }
  }
#pragma unroll
  for (int o = 1; o < 16; o <<= 1)
#pragma unroll
    for (int r = 0; r < 4; ++r) mr[r] = fmaxf(mr[r], __shfl_xor(mr[r], o, 16));
#pragma unroll
  for (int kt = 0; kt < 16; ++kt)
#pragma unroll
    for (int r = 0; r < 4; ++r) {
      float e = __expf(sacc[kt][r] - mr[r]);
      sacc[kt][r] = e;
      sr[r] += e;
    }
#pragma unroll
  for (int o = 1; o < 16; o <<= 1)
#pragma unroll
    for (int r = 0; r < 4; ++r) sr[r] += __shfl_xor(sr[r], o, 16);
#pragma unroll
  for (int r = 0; r < 4; ++r) sr[r] = 1.f / sr[r];

  // P -> LDS (swizzled): row = l4*4+r, colbyte = (kt*16+l15)*2
#pragma unroll
  for (int kt = 0; kt < 16; ++kt)
#pragma unroll
    for (int r = 0; r < 4; ++r) {
      const int row = l4 * 4 + r;
      *(ushort_t*)((char*)Ps + row * 512 + (((kt * 16 + l15) * 2) ^ ((row & 7) << 4))) =
          f2b(sacc[kt][r] * sr[r]);
    }

  // P fragments: row = l15, keybytes = ks*64 + l4*16
  bf16x8 pf[8];
#pragma unroll
  for (int ks = 0; ks < 8; ++ks)
    pf[ks] = *(const bf16x8*)((const char*)Ps + l15 * 512 + ((ks * 64 + l4 * 16) ^ ((l15 & 7) << 4)));

  // O = P V   (V^T fragments from L2: dk-row = dt*16+l15, key = ks*32+l4*8)
  f32x4 oacc[16] = {};
  const ushort_t* vp = vT + ((long)bh << 16) + (long)l15 * 256 + l4 * 8;
#pragma unroll 2
  for (int dt = 0; dt < 16; ++dt) {
    bf16x8 vf[8];
#pragma unroll
    for (int ks = 0; ks < 8; ++ks)
      vf[ks] = *(const bf16x8*)(vp + dt * 16 * 256 + ks * 32);
#pragma unroll
    for (int ks = 0; ks < 8; ++ks)
      oacc[dt] = __builtin_amdgcn_mfma_f32_16x16x32_bf16(pf[ks], vf[ks], oacc[dt], 0, 0, 0);
  }

  // O -> LDS (reuse Ps, swizzled) -> coalesced 16B stores
#pragma unroll
  for (int dt = 0; dt < 16; ++dt)
#pragma unroll
    for (int r = 0; r < 4; ++r) {
      const int row = l4 * 4 + r;
      *(ushort_t*)((char*)Ps + row * 512 + (((dt * 16 + l15) * 2) ^ ((row & 7) << 4))) =
          f2b(oacc[dt][r]);
    }
  ushort_t* dst = ao + (long)(b * 256 + q0 + l15) * 2048 + h * 256 + l4 * 64;
#pragma unroll
  for (int m = 0; m < 8; ++m) {
    const int cbyte = l4 * 128 + m * 16;
    u16x8 v = *(const u16x8*)((const char*)Ps + l15 * 512 + (cbyte ^ ((l15 & 7) << 4)));
    *(u16x8*)(dst + m * 8) = v;
  }
}

// x = data*sqrt(D) + pe + seg_emb[view_idx*S]
__global__ __launch_bounds__(256)
void build_x(const float* __restrict__ data, const float* __restrict__ seg,
             const int* __restrict__ viewp, float* __restrict__ x)
{
  int i = blockIdx.x * 256 + threadIdx.x;
  int d = i & 511;
  int s = (i >> 9) & 255;
  float ang = (float)s * exp2f((float)d * -0.03125f);
  float pe = (d & 1) ? cosf(ang) : sinf(ang);
  int vrow = viewp[0] * SS;
  x[i] = data[i] * 22.627416997969522f + pe + seg[vrow * DIM + d];
}

// LayerNorm with optional fused residual: x += sum(parts[0..np)), write back,
// then normalize (unbiased var, eps on std). outB: bf16 out; outF: fp32 out.
__global__ __launch_bounds__(256)
void lnorm_k(const float* __restrict__ x, const float* __restrict__ parts, int np,
             float* __restrict__ xout,
             const float* __restrict__ alpha, const float* __restrict__ beta,
             ushort_t* __restrict__ outB, float* __restrict__ outF)
{
  const int row = blockIdx.x, tid = threadIdx.x;
  const long base = (long)row * DIM;
  float2 v = ((const float2*)(x + base))[tid];
  if (np) {
    for (int p = 0; p < np; ++p) {
      float2 a = ((const float2*)(parts + (long)p * 1048576 + base))[tid];
      v.x += a.x; v.y += a.y;
    }
    ((float2*)(xout + base))[tid] = v;
  }
  float s = v.x + v.y;
#pragma unroll
  for (int o = 32; o; o >>= 1) s += __shfl_xor(s, o, 64);
  __shared__ float rs[4], rq[4];
  if ((tid & 63) == 0) rs[tid >> 6] = s;
  __syncthreads();
  const float mu = (rs[0] + rs[1] + rs[2] + rs[3]) * (1.f / 512.f);
  const float dx = v.x - mu, dy = v.y - mu;
  float q = dx * dx + dy * dy;
#pragma unroll
  for (int o = 32; o; o >>= 1) q += __shfl_xor(q, o, 64);
  if ((tid & 63) == 0) rq[tid >> 6] = q;
  __syncthreads();
  const float var = (rq[0] + rq[1] + rq[2] + rq[3]) * (1.f / 511.f);
  const float rstd = 1.f / (sqrtf(var) + 1e-6f);
  const int d0 = tid * 2;
  const float o0 = alpha[d0] * dx * rstd + beta[d0];
  const float o1 = alpha[d0 + 1] * dy * rstd + beta[d0 + 1];
  if (outB) { outB[base + d0] = f2b(o0); outB[base + d0 + 1] = f2b(o1); }
  else      { outF[base + d0] = o0;      outF[base + d0 + 1] = o1; }
}

// fp32 [R,C] -> bf16 [C,R], per-z with output z-stride (elements)
__global__ __launch_bounds__(256)
void wtrans(const float* __restrict__ in, ushort_t* __restrict__ out,
            int R, int C, long ozs)
{
  __shared__ float t[32][33];
  const int z = blockIdx.z;
  const long zi = (long)z * R * C, zo = (long)z * ozs;
  const int c0 = blockIdx.x * 32, r0 = blockIdx.y * 32;
  const int tx = threadIdx.x & 31, ty = threadIdx.x >> 5;
#pragma unroll
  for (int i = 0; i < 4; ++i) t[ty + i * 8][tx] = in[zi + (long)(r0 + ty + i * 8) * C + c0 + tx];
  __syncthreads();
#pragma unroll
  for (int i = 0; i < 4; ++i) out[zo + (long)(c0 + ty + i * 8) * R + r0 + tx] = f2b(t[tx][ty + i * 8]);
}

extern "C" void kernel_launch(void* const* d_in, const int* in_sizes, int n_in,
                              void* d_out, int out_size, void* d_ws, size_t ws_size,
                              hipStream_t stream)
{
  const float* data  = (const float*)d_in[0];
  const int*   attnm = (const int*)d_in[1];
  const int*   viewp = (const int*)d_in[2];
  const float* seg   = (const float*)d_in[3];
  const float* Wq    = (const float*)d_in[4];
  const float* bq    = (const float*)d_in[5];
  const float* Wk    = (const float*)d_in[6];
  const float* bk    = (const float*)d_in[7];
  const float* Wv    = (const float*)d_in[8];
  const float* bv    = (const float*)d_in[9];
  const float* Wo    = (const float*)d_in[10];
  const float* bo    = (const float*)d_in[11];
  const float* W1    = (const float*)d_in[12];
  const float* b1    = (const float*)d_in[13];
  const float* W2    = (const float*)d_in[14];
  const float* b2    = (const float*)d_in[15];
  const float* al1   = (const float*)d_in[16];
  const float* be1   = (const float*)d_in[17];
  const float* al2   = (const float*)d_in[18];
  const float* be2   = (const float*)d_in[19];
  const float* alf   = (const float*)d_in[20];
  const float* bef   = (const float*)d_in[21];

  char* w = (char*)d_ws;
  const size_t MB = 1024 * 1024;
  ushort_t* qkvW = (ushort_t*)(w + 0 * MB);   // [L][6144][512] bf16
  ushort_t* WoT  = (ushort_t*)(w + 24 * MB);  // [L][512][2048]
  ushort_t* W1T  = (ushort_t*)(w + 32 * MB);  // [L][2048][512]
  ushort_t* W2T  = (ushort_t*)(w + 40 * MB);  // [L][512][2048]
  float*    x    = (float*)   (w + 48 * MB);  // [2048][512] fp32
  ushort_t* x2   = (ushort_t*)(w + 52 * MB);  // [2048][512] bf16
  ushort_t* qb   = (ushort_t*)(w + 54 * MB);  // [2048][2048] bf16
  ushort_t* kbf  = (ushort_t*)(w + 62 * MB);
  ushort_t* vT   = (ushort_t*)(w + 70 * MB);  // [64][256][256]
  ushort_t* ao   = (ushort_t*)(w + 78 * MB);  // [2048][2048]
  ushort_t* ffh  = (ushort_t*)(w + 86 * MB);  // [2048][2048]
  float*    parts= (float*)   (w + 94 * MB);  // 4 x [2048][512] fp32 (94..110MB)

  dim3 blk(256);
  const long QKV_L = 6144L * 512;
  wtrans<<<dim3(64, 16, 4), blk, 0, stream>>>(Wq, qkvW + 0 * 2048 * 512, 512, 2048, QKV_L);
  wtrans<<<dim3(64, 16, 4), blk, 0, stream>>>(Wk, qkvW + 1 * 2048 * 512, 512, 2048, QKV_L);
  wtrans<<<dim3(64, 16, 4), blk, 0, stream>>>(Wv, qkvW + 2 * 2048 * 512, 512, 2048, QKV_L);
  wtrans<<<dim3(16, 64, 4), blk, 0, stream>>>(Wo, WoT, 2048, 512, 512L * 2048);
  wtrans<<<dim3(64, 16, 4), blk, 0, stream>>>(W1, W1T, 512, 2048, 2048L * 512);
  wtrans<<<dim3(16, 64, 4), blk, 0, stream>>>(W2, W2T, 2048, 512, 512L * 2048);
  build_x<<<4096, blk, 0, stream>>>(data, seg, viewp, x);

  for (int i = 0; i < LNUM; ++i) {
    if (i == 0)
      lnorm_k<<<2048, blk, 0, stream>>>(x, nullptr, 0, nullptr, al1, be1, x2, nullptr);
    // fused QKV: [2048,512] x [6144,512]^T ; V repacked via LDS to vT
    gemm_bt<128, 64, 3><<<dim3(96, 16, 1), blk, 0, stream>>>(
        x2, qkvW + (long)i * QKV_L, bq + i * 2048, bk + i * 2048, bv + i * 2048,
        qb, kbf, vT, nullptr, 512, 512, 512, 2048, 1, 0);
    attn_k<<<dim3(1024), dim3(64), 0, stream>>>(qb, kbf, vT, attnm, ao);
    // Wo: [2048,2048] x [512,2048]^T, split-K=4 -> parts
    gemm_bt<64, 64, 2><<<dim3(8, 32, 4), blk, 0, stream>>>(
        ao, WoT + (long)i * 512 * 2048, bo + i * 512, nullptr, nullptr,
        nullptr, nullptr, nullptr, parts, 2048, 2048, 2048, 512, 4, 0);
    lnorm_k<<<2048, blk, 0, stream>>>(x, parts, 4, x, al2 + i * 512, be2 + i * 512, x2, nullptr);
    // FF1: [2048,512] x [2048,512]^T, relu
    gemm_bt<128, 64, 0><<<dim3(32, 16, 1), blk, 0, stream>>>(
        x2, W1T + (long)i * 2048 * 512, b1 + i * 2048, nullptr, nullptr,
        ffh, nullptr, nullptr, nullptr, 512, 512, 512, 2048, 1, 1);
    // FF2: [2048,2048] x [512,2048]^T, split-K=4 -> parts
    gemm_bt<64, 64, 2><<<dim3(8, 32, 4), blk, 0, stream>>>(
        ffh, W2T + (long)i * 512 * 2048, b2 + i * 512, nullptr, nullptr,
        nullptr, nullptr, nullptr, parts, 2048, 2048, 2048, 512, 4, 0);
    if (i < LNUM - 1)
      lnorm_k<<<2048, blk, 0, stream>>>(x, parts, 4, x, al1 + (i + 1) * 512, be1 + (i + 1) * 512, x2, nullptr);
    else
      lnorm_k<<<2048, blk, 0, stream>>>(x, parts, 4, x, alf, bef, nullptr, (float*)d_out);
  }
}

// Round 7
// 527.497 us; speedup vs baseline: 1.1692x; 1.1435x over previous
//
#include <hip/hip_runtime.h>
#include <hip/hip_bf16.h>

#define LNUM 4
#define DIM  512
#define SS   256

typedef unsigned short ushort_t;
typedef __attribute__((ext_vector_type(8))) short bf16x8;
typedef __attribute__((ext_vector_type(4))) float f32x4;
typedef __attribute__((ext_vector_type(8))) unsigned short u16x8;

#define VWAIT(n) asm volatile("s_waitcnt vmcnt(" #n ")" ::: "memory")
__device__ __forceinline__ void bar() { __builtin_amdgcn_s_barrier(); }

__device__ __forceinline__ ushort_t f2b(float f) {
  union { float f; unsigned u; } x; x.f = f;
  unsigned r = x.u + 0x7FFFu + ((x.u >> 16) & 1u);
  return (ushort_t)(r >> 16);
}

__device__ __forceinline__ void gload16(const void* g, void* s) {
  __builtin_amdgcn_global_load_lds((const __attribute__((address_space(1))) void*)g,
                                   (__attribute__((address_space(3))) void*)s, 16, 0, 0);
}

// ---------------------------------------------------------------------------
// C = A * B^T, 3-buffer depth-2 pipeline, counted vmcnt, raw barriers.
// EPI 0: outB = bf16(acc + bias) [relu opt]
// EPI 2: outF[kz partial] = acc + bias(kz==0)   (plain fp32 store)
// EPI 3: fused QKV routing; V segment repacked via LDS -> vT coalesced
// ---------------------------------------------------------------------------
template<int TM, int TN, int EPI>
__global__ __launch_bounds__(256, 2)
void gemm_bt(const ushort_t* __restrict__ A, const ushort_t* __restrict__ B,
             const float* __restrict__ bias, const float* __restrict__ bias2,
             const float* __restrict__ bias3,
             ushort_t* __restrict__ outB, ushort_t* __restrict__ outB2,
             ushort_t* __restrict__ outB3, float* __restrict__ outF,
             int K, int lda, int ldb, int ldc, int nkz, int relu)
{
  constexpr int CA = TM / 32, CB = TN / 32, SN = CA + CB;
  constexpr int WM = TM / 32, WN = TN / 32;
  __shared__ ushort_t As[3 * TM * 64];
  __shared__ ushort_t Bs[3 * TN * 64];
  const int tid = threadIdx.x, lane = tid & 63, wid = tid >> 6;
  const int wm = wid >> 1, wn = wid & 1;
  const int kz = blockIdx.z, Kz = K / nkz, k0 = kz * Kz, nt = Kz >> 6;

  const ushort_t* Ab = A + (long)blockIdx.y * TM * lda + k0;
  const ushort_t* Bb = B + (long)blockIdx.x * TN * ldb + k0;

  const ushort_t* srcA[CA]; ushort_t* ldsA[CA];
  const ushort_t* srcB[CB]; ushort_t* ldsB[CB];
#pragma unroll
  for (int c = 0; c < CA; ++c) {
    int off = c * 4096 + tid * 16;
    int row = off >> 7;
    int scol = ((off & 127) ^ ((row & 7) << 4)) >> 1;
    srcA[c] = Ab + (long)row * lda + scol;
    ldsA[c] = As + c * 2048 + wid * 512;
  }
#pragma unroll
  for (int c = 0; c < CB; ++c) {
    int off = c * 4096 + tid * 16;
    int row = off >> 7;
    int scol = ((off & 127) ^ ((row & 7) << 4)) >> 1;
    srcB[c] = Bb + (long)row * ldb + scol;
    ldsB[c] = Bs + c * 2048 + wid * 512;
  }

  f32x4 acc[WM][WN] = {};

  auto STAGE = [&](int buf, int t) {
#pragma unroll
    for (int c = 0; c < CA; ++c) gload16(srcA[c] + t * 64, ldsA[c] + buf * TM * 64);
#pragma unroll
    for (int c = 0; c < CB; ++c) gload16(srcB[c] + t * 64, ldsB[c] + buf * TN * 64);
  };

  STAGE(0, 0);
  STAGE(1, 1);
  for (int t = 0; t < nt; ++t) {
    if (t < nt - 1) { if constexpr (SN == 6) VWAIT(6); else VWAIT(4); }
    else VWAIT(0);
    bar();
    if (t + 2 < nt) STAGE((t + 2) % 3, t + 2);
    const int buf = t % 3;
#pragma unroll
    for (int ks = 0; ks < 2; ++ks) {
      const int kb = ks * 64 + ((lane >> 4) << 4);
      bf16x8 af[WM], bfr[WN];
#pragma unroll
      for (int f = 0; f < WM; ++f) {
        int ra = wm * (TM / 2) + f * 16 + (lane & 15);
        af[f] = *(const bf16x8*)((const char*)As + buf * TM * 128 + ra * 128 + (kb ^ ((ra & 7) << 4)));
      }
#pragma unroll
      for (int g = 0; g < WN; ++g) {
        int rb = wn * (TN / 2) + g * 16 + (lane & 15);
        bfr[g] = *(const bf16x8*)((const char*)Bs + buf * TN * 128 + rb * 128 + (kb ^ ((rb & 7) << 4)));
      }
      __builtin_amdgcn_s_setprio(1);
#pragma unroll
      for (int i = 0; i < WM; ++i)
#pragma unroll
        for (int j = 0; j < WN; ++j)
          acc[i][j] = __builtin_amdgcn_mfma_f32_16x16x32_bf16(af[i], bfr[j], acc[i][j], 0, 0, 0);
      __builtin_amdgcn_s_setprio(0);
    }
  }

  const int row0 = blockIdx.y * TM + wm * (TM / 2) + ((lane >> 4) << 2);
  int col0 = blockIdx.x * TN + wn * (TN / 2) + (lane & 15);
  const float* bsel = bias;
  ushort_t* osel = outB;
  int seg = 0;
  if (EPI == 3) {
    seg = (blockIdx.x * TN) >> 11;
    if (seg == 1) { bsel = bias2; osel = outB2; }
    else if (seg == 2) { bsel = bias3; }
    col0 -= seg * 2048;
  }

  if (EPI == 3 && seg == 2) {
    // V segment: repack 128(row) x 64(col) tile via LDS, write vT[bh][dk][s]
    ushort_t* Vt = As;              // reuse staging LDS (padded stride 136)
    bar();                          // all waves done reading As
#pragma unroll
    for (int i = 0; i < WM; ++i)
#pragma unroll
      for (int j = 0; j < WN; ++j) {
        const int colL = wn * (TN / 2) + j * 16 + (lane & 15);
        const float bv = bsel[(col0 + j * 16) & 2047];
#pragma unroll
        for (int r = 0; r < 4; ++r) {
          const int rowL = wm * (TM / 2) + i * 16 + ((lane >> 4) << 2) + r;
          Vt[colL * 136 + rowL] = f2b(acc[i][j][r] + bv);
        }
      }
    bar();
    const int colvBase = blockIdx.x * TN - 4096;         // within V's 2048 cols
    const int h = colvBase >> 8, dk0 = colvBase & 255;
    const int rowBase = blockIdx.y * TM;
    const int bh = ((rowBase >> 8) << 3) + h;
    const int s0 = rowBase & 255;
    const int dkl = tid >> 2, scc = (tid & 3) * 32;
    ushort_t* dst = outB3 + ((long)bh << 16) + (long)(dk0 + dkl) * 256 + s0 + scc;
#pragma unroll
    for (int m = 0; m < 4; ++m)
      *(u16x8*)(dst + m * 8) = *(const u16x8*)(Vt + dkl * 136 + scc + m * 8);
    return;
  }

#pragma unroll
  for (int i = 0; i < WM; ++i) {
#pragma unroll
    for (int j = 0; j < WN; ++j) {
      const int col = col0 + j * 16;
      float bv;
      if (EPI == 2) bv = (kz == 0) ? bias[col] : 0.f;
      else          bv = bsel[col];
#pragma unroll
      for (int r = 0; r < 4; ++r) {
        const int row = row0 + i * 16 + r;
        float v = acc[i][j][r] + bv;
        if (EPI == 2) {
          outF[(long)kz * 1048576 + (long)row * ldc + col] = v;
        } else {
          if (relu) v = fmaxf(v, 0.f);
          osel[(long)row * ldc + col] = f2b(v);
        }
      }
    }
  }
}

// ---------------------------------------------------------------------------
// Attention: one wave (64 threads) per (16-row q-tile, head). XCD-aware block
// mapping keeps all 16 q-tiles of a head on one XCD (8 heads/XCD -> K/V L2-
// resident). Q/S/O in registers (FULLY static indexing -> no scratch);
// K,V fragments loaded straight from L2; P and the O repack make one 8KB
// swizzled-LDS round trip each.
// ---------------------------------------------------------------------------
__global__ __launch_bounds__(64, 2)
void attn_k(const ushort_t* __restrict__ qb, const ushort_t* __restrict__ kbf,
            const ushort_t* __restrict__ vT, const int* __restrict__ attnm,
            ushort_t* __restrict__ ao)
{
  __shared__ ushort_t Ps[16 * 256];          // 8KB, XOR-swizzled rows
  const int i = blockIdx.x;
  const int xcd = i & 7, slot = i >> 3;
  const int bh = xcd + 8 * (slot >> 4);      // all 16 q-tiles of bh on one XCD
  const int qt = slot & 15;
  const int b = bh >> 3, h = bh & 7;
  const int lane = threadIdx.x;
  const int l15 = lane & 15, l4 = lane >> 4;
  const int q0 = qt * 16;

  // pack key mask into bits (bit kt = mask of key kt*16+l15)
  unsigned mbits = 0;
#pragma unroll
  for (int kt = 0; kt < 16; ++kt)
    mbits |= (attnm[b * 256 + kt * 16 + l15] != 0 ? 1u : 0u) << kt;

  // Q fragments: row = q0+l15, k = ks*32 + l4*8
  const ushort_t* qp = qb + (long)(b * 256 + q0 + l15) * 2048 + h * 256 + l4 * 8;
  bf16x8 qf[8];
#pragma unroll
  for (int ks = 0; ks < 8; ++ks) qf[ks] = *(const bf16x8*)(qp + ks * 32);

  // S = Q K^T  (fully unrolled: static acc indexing, regs not scratch)
  f32x4 sacc[16] = {};
  const ushort_t* kp = kbf + (long)(b * 256 + l15) * 2048 + h * 256 + l4 * 8;
#pragma unroll
  for (int kt = 0; kt < 16; ++kt) {
    bf16x8 kf[8];
#pragma unroll
    for (int ks = 0; ks < 8; ++ks)
      kf[ks] = *(const bf16x8*)(kp + (long)kt * 16 * 2048 + ks * 32);
#pragma unroll
    for (int ks = 0; ks < 8; ++ks)
      sacc[kt] = __builtin_amdgcn_mfma_f32_16x16x32_bf16(qf[ks], kf[ks], sacc[kt], 0, 0, 0);
  }

  // softmax over 256 keys; lane holds keys kt*16+l15 for q-rows l4*4+r
  float mr[4] = {-3e38f, -3e38f, -3e38f, -3e38f}, sr[4] = {};
#pragma unroll
  for (int kt = 0; kt < 16; ++kt) {
    const bool mk = (mbits >> kt) & 1;
#pragma unroll
    for (int r = 0; r < 4; ++r) {
      float s = mk ? -1e9f : sacc[kt][r] * 0.0625f;
      sacc[kt][r] = s;
      mr[r] = fmaxf(mr[r], s);
    }
  }
#pragma unroll
  for (int o = 1; o < 16; o <<= 1)
#pragma unroll
    for (int r = 0; r < 4; ++r) mr[r] = fmaxf(mr[r], __shfl_xor(mr[r], o, 16));
#pragma unroll
  for (int kt = 0; kt < 16; ++kt)
#pragma unroll
    for (int r = 0; r < 4; ++r) {
      float e = __expf(sacc[kt][r] - mr[r]);
      sacc[kt][r] = e;
      sr[r] += e;
    }
#pragma unroll
  for (int o = 1; o < 16; o <<= 1)
#pragma unroll
    for (int r = 0; r < 4; ++r) sr[r] += __shfl_xor(sr[r], o, 16);
#pragma unroll
  for (int r = 0; r < 4; ++r) sr[r] = 1.f / sr[r];

  // P -> LDS (swizzled): row = l4*4+r, colbyte = (kt*16+l15)*2
#pragma unroll
  for (int kt = 0; kt < 16; ++kt)
#pragma unroll
    for (int r = 0; r < 4; ++r) {
      const int row = l4 * 4 + r;
      *(ushort_t*)((char*)Ps + row * 512 + (((kt * 16 + l15) * 2) ^ ((row & 7) << 4))) =
          f2b(sacc[kt][r] * sr[r]);
    }

  // P fragments: row = l15, keybytes = ks*64 + l4*16
  bf16x8 pf[8];
#pragma unroll
  for (int ks = 0; ks < 8; ++ks)
    pf[ks] = *(const bf16x8*)((const char*)Ps + l15 * 512 + ((ks * 64 + l4 * 16) ^ ((l15 & 7) << 4)));

  // O = P V   (V^T fragments from L2: dk-row = dt*16+l15, key = ks*32+l4*8)
  f32x4 oacc[16] = {};
  const ushort_t* vp = vT + ((long)bh << 16) + (long)l15 * 256 + l4 * 8;
#pragma unroll
  for (int dt = 0; dt < 16; ++dt) {
    bf16x8 vf[8];
#pragma unroll
    for (int ks = 0; ks < 8; ++ks)
      vf[ks] = *(const bf16x8*)(vp + dt * 16 * 256 + ks * 32);
#pragma unroll
    for (int ks = 0; ks < 8; ++ks)
      oacc[dt] = __builtin_amdgcn_mfma_f32_16x16x32_bf16(pf[ks], vf[ks], oacc[dt], 0, 0, 0);
  }

  // O -> LDS (reuse Ps, swizzled) -> coalesced 16B stores
#pragma unroll
  for (int dt = 0; dt < 16; ++dt)
#pragma unroll
    for (int r = 0; r < 4; ++r) {
      const int row = l4 * 4 + r;
      *(ushort_t*)((char*)Ps + row * 512 + (((dt * 16 + l15) * 2) ^ ((row & 7) << 4))) =
          f2b(oacc[dt][r]);
    }
  ushort_t* dst = ao + (long)(b * 256 + q0 + l15) * 2048 + h * 256 + l4 * 64;
#pragma unroll
  for (int m = 0; m < 8; ++m) {
    const int cbyte = l4 * 128 + m * 16;
    u16x8 v = *(const u16x8*)((const char*)Ps + l15 * 512 + (cbyte ^ ((l15 & 7) << 4)));
    *(u16x8*)(dst + m * 8) = v;
  }
}

// x = data*sqrt(D) + pe + seg_emb[view_idx*S]
__global__ __launch_bounds__(256)
void build_x(const float* __restrict__ data, const float* __restrict__ seg,
             const int* __restrict__ viewp, float* __restrict__ x)
{
  int i = blockIdx.x * 256 + threadIdx.x;
  int d = i & 511;
  int s = (i >> 9) & 255;
  float ang = (float)s * exp2f((float)d * -0.03125f);
  float pe = (d & 1) ? cosf(ang) : sinf(ang);
  int vrow = viewp[0] * SS;
  x[i] = data[i] * 22.627416997969522f + pe + seg[vrow * DIM + d];
}

// LayerNorm with optional fused residual: x += sum(parts[0..np)), write back,
// then normalize (unbiased var, eps on std). outB: bf16 out; outF: fp32 out.
__global__ __launch_bounds__(256)
void lnorm_k(const float* __restrict__ x, const float* __restrict__ parts, int np,
             float* __restrict__ xout,
             const float* __restrict__ alpha, const float* __restrict__ beta,
             ushort_t* __restrict__ outB, float* __restrict__ outF)
{
  const int row = blockIdx.x, tid = threadIdx.x;
  const long base = (long)row * DIM;
  float2 v = ((const float2*)(x + base))[tid];
  if (np) {
    for (int p = 0; p < np; ++p) {
      float2 a = ((const float2*)(parts + (long)p * 1048576 + base))[tid];
      v.x += a.x; v.y += a.y;
    }
    ((float2*)(xout + base))[tid] = v;
  }
  float s = v.x + v.y;
#pragma unroll
  for (int o = 32; o; o >>= 1) s += __shfl_xor(s, o, 64);
  __shared__ float rs[4], rq[4];
  if ((tid & 63) == 0) rs[tid >> 6] = s;
  __syncthreads();
  const float mu = (rs[0] + rs[1] + rs[2] + rs[3]) * (1.f / 512.f);
  const float dx = v.x - mu, dy = v.y - mu;
  float q = dx * dx + dy * dy;
#pragma unroll
  for (int o = 32; o; o >>= 1) q += __shfl_xor(q, o, 64);
  if ((tid & 63) == 0) rq[tid >> 6] = q;
  __syncthreads();
  const float var = (rq[0] + rq[1] + rq[2] + rq[3]) * (1.f / 511.f);
  const float rstd = 1.f / (sqrtf(var) + 1e-6f);
  const int d0 = tid * 2;
  const float o0 = alpha[d0] * dx * rstd + beta[d0];
  const float o1 = alpha[d0 + 1] * dy * rstd + beta[d0 + 1];
  if (outB) { outB[base + d0] = f2b(o0); outB[base + d0 + 1] = f2b(o1); }
  else      { outF[base + d0] = o0;      outF[base + d0 + 1] = o1; }
}

// fp32 [R,C] -> bf16 [C,R], per-z with output z-stride (elements)
__global__ __launch_bounds__(256)
void wtrans(const float* __restrict__ in, ushort_t* __restrict__ out,
            int R, int C, long ozs)
{
  __shared__ float t[32][33];
  const int z = blockIdx.z;
  const long zi = (long)z * R * C, zo = (long)z * ozs;
  const int c0 = blockIdx.x * 32, r0 = blockIdx.y * 32;
  const int tx = threadIdx.x & 31, ty = threadIdx.x >> 5;
#pragma unroll
  for (int i = 0; i < 4; ++i) t[ty + i * 8][tx] = in[zi + (long)(r0 + ty + i * 8) * C + c0 + tx];
  __syncthreads();
#pragma unroll
  for (int i = 0; i < 4; ++i) out[zo + (long)(c0 + ty + i * 8) * R + r0 + tx] = f2b(t[tx][ty + i * 8]);
}

extern "C" void kernel_launch(void* const* d_in, const int* in_sizes, int n_in,
                              void* d_out, int out_size, void* d_ws, size_t ws_size,
                              hipStream_t stream)
{
  const float* data  = (const float*)d_in[0];
  const int*   attnm = (const int*)d_in[1];
  const int*   viewp = (const int*)d_in[2];
  const float* seg   = (const float*)d_in[3];
  const float* Wq    = (const float*)d_in[4];
  const float* bq    = (const float*)d_in[5];
  const float* Wk    = (const float*)d_in[6];
  const float* bk    = (const float*)d_in[7];
  const float* Wv    = (const float*)d_in[8];
  const float* bv    = (const float*)d_in[9];
  const float* Wo    = (const float*)d_in[10];
  const float* bo    = (const float*)d_in[11];
  const float* W1    = (const float*)d_in[12];
  const float* b1    = (const float*)d_in[13];
  const float* W2    = (const float*)d_in[14];
  const float* b2    = (const float*)d_in[15];
  const float* al1   = (const float*)d_in[16];
  const float* be1   = (const float*)d_in[17];
  const float* al2   = (const float*)d_in[18];
  const float* be2   = (const float*)d_in[19];
  const float* alf   = (const float*)d_in[20];
  const float* bef   = (const float*)d_in[21];

  char* w = (char*)d_ws;
  const size_t MB = 1024 * 1024;
  ushort_t* qkvW = (ushort_t*)(w + 0 * MB);   // [L][6144][512] bf16
  ushort_t* WoT  = (ushort_t*)(w + 24 * MB);  // [L][512][2048]
  ushort_t* W1T  = (ushort_t*)(w + 32 * MB);  // [L][2048][512]
  ushort_t* W2T  = (ushort_t*)(w + 40 * MB);  // [L][512][2048]
  float*    x    = (float*)   (w + 48 * MB);  // [2048][512] fp32
  ushort_t* x2   = (ushort_t*)(w + 52 * MB);  // [2048][512] bf16
  ushort_t* qb   = (ushort_t*)(w + 54 * MB);  // [2048][2048] bf16
  ushort_t* kbf  = (ushort_t*)(w + 62 * MB);
  ushort_t* vT   = (ushort_t*)(w + 70 * MB);  // [64][256][256]
  ushort_t* ao   = (ushort_t*)(w + 78 * MB);  // [2048][2048]
  ushort_t* ffh  = (ushort_t*)(w + 86 * MB);  // [2048][2048]
  float*    parts= (float*)   (w + 94 * MB);  // 4 x [2048][512] fp32 (94..110MB)

  dim3 blk(256);
  const long QKV_L = 6144L * 512;
  wtrans<<<dim3(64, 16, 4), blk, 0, stream>>>(Wq, qkvW + 0 * 2048 * 512, 512, 2048, QKV_L);
  wtrans<<<dim3(64, 16, 4), blk, 0, stream>>>(Wk, qkvW + 1 * 2048 * 512, 512, 2048, QKV_L);
  wtrans<<<dim3(64, 16, 4), blk, 0, stream>>>(Wv, qkvW + 2 * 2048 * 512, 512, 2048, QKV_L);
  wtrans<<<dim3(16, 64, 4), blk, 0, stream>>>(Wo, WoT, 2048, 512, 512L * 2048);
  wtrans<<<dim3(64, 16, 4), blk, 0, stream>>>(W1, W1T, 512, 2048, 2048L * 512);
  wtrans<<<dim3(16, 64, 4), blk, 0, stream>>>(W2, W2T, 2048, 512, 512L * 2048);
  build_x<<<4096, blk, 0, stream>>>(data, seg, viewp, x);

  for (int i = 0; i < LNUM; ++i) {
    if (i == 0)
      lnorm_k<<<2048, blk, 0, stream>>>(x, nullptr, 0, nullptr, al1, be1, x2, nullptr);
    // fused QKV: [2048,512] x [6144,512]^T ; V repacked via LDS to vT
    gemm_bt<128, 64, 3><<<dim3(96, 16, 1), blk, 0, stream>>>(
        x2, qkvW + (long)i * QKV_L, bq + i * 2048, bk + i * 2048, bv + i * 2048,
        qb, kbf, vT, nullptr, 512, 512, 512, 2048, 1, 0);
    attn_k<<<dim3(1024), dim3(64), 0, stream>>>(qb, kbf, vT, attnm, ao);
    // Wo: [2048,2048] x [512,2048]^T, split-K=4 -> parts
    gemm_bt<64, 64, 2><<<dim3(8, 32, 4), blk, 0, stream>>>(
        ao, WoT + (long)i * 512 * 2048, bo + i * 512, nullptr, nullptr,
        nullptr, nullptr, nullptr, parts, 2048, 2048, 2048, 512, 4, 0);
    lnorm_k<<<2048, blk, 0, stream>>>(x, parts, 4, x, al2 + i * 512, be2 + i * 512, x2, nullptr);
    // FF1: [2048,512] x [2048,512]^T, relu
    gemm_bt<128, 64, 0><<<dim3(32, 16, 1), blk, 0, stream>>>(
        x2, W1T + (long)i * 2048 * 512, b1 + i * 2048, nullptr, nullptr,
        ffh, nullptr, nullptr, nullptr, 512, 512, 512, 2048, 1, 1);
    // FF2: [2048,2048] x [512,2048]^T, split-K=4 -> parts
    gemm_bt<64, 64, 2><<<dim3(8, 32, 4), blk, 0, stream>>>(
        ffh, W2T + (long)i * 512 * 2048, b2 + i * 512, nullptr, nullptr,
        nullptr, nullptr, nullptr, parts, 2048, 2048, 2048, 512, 4, 0);
    if (i < LNUM - 1)
      lnorm_k<<<2048, blk, 0, stream>>>(x, parts, 4, x, al1 + (i + 1) * 512, be1 + (i + 1) * 512, x2, nullptr);
    else
      lnorm_k<<<2048, blk, 0, stream>>>(x, parts, 4, x, alf, bef, nullptr, (float*)d_out);
  }
}

// Round 8
// 485.452 us; speedup vs baseline: 1.2705x; 1.0866x over previous
//
#include <hip/hip_runtime.h>
#include <hip/hip_bf16.h>

#define LNUM 4
#define DIM  512
#define SS   256

typedef unsigned short ushort_t;
typedef __attribute__((ext_vector_type(8))) short bf16x8;
typedef __attribute__((ext_vector_type(4))) float f32x4;
typedef __attribute__((ext_vector_type(8))) unsigned short u16x8;

#define VWAIT(n) asm volatile("s_waitcnt vmcnt(" #n ")" ::: "memory")
__device__ __forceinline__ void bar() { __builtin_amdgcn_s_barrier(); }

__device__ __forceinline__ ushort_t f2b(float f) {
  union { float f; unsigned u; } x; x.f = f;
  unsigned r = x.u + 0x7FFFu + ((x.u >> 16) & 1u);
  return (ushort_t)(r >> 16);
}

__device__ __forceinline__ void gload16(const void* g, void* s) {
  __builtin_amdgcn_global_load_lds((const __attribute__((address_space(1))) void*)g,
                                   (__attribute__((address_space(3))) void*)s, 16, 0, 0);
}

// ---------------------------------------------------------------------------
// C = A * B^T, 3-buffer depth-2 pipeline, counted vmcnt, raw barriers.
// EPI 0: outB = bf16(acc + bias) [relu opt]
// EPI 2: outF[kz partial] = acc + bias(kz==0)   (plain fp32 store)
// EPI 3: fused QKV routing; Q,K written head-major [bh][s][dk];
//        V segment repacked via LDS -> vT coalesced
// ---------------------------------------------------------------------------
template<int TM, int TN, int EPI>
__global__ __launch_bounds__(256, 2)
void gemm_bt(const ushort_t* __restrict__ A, const ushort_t* __restrict__ B,
             const float* __restrict__ bias, const float* __restrict__ bias2,
             const float* __restrict__ bias3,
             ushort_t* __restrict__ outB, ushort_t* __restrict__ outB2,
             ushort_t* __restrict__ outB3, float* __restrict__ outF,
             int K, int lda, int ldb, int ldc, int nkz, int relu)
{
  constexpr int CA = TM / 32, CB = TN / 32, SN = CA + CB;
  constexpr int WM = TM / 32, WN = TN / 32;
  __shared__ ushort_t As[3 * TM * 64];
  __shared__ ushort_t Bs[3 * TN * 64];
  const int tid = threadIdx.x, lane = tid & 63, wid = tid >> 6;
  const int wm = wid >> 1, wn = wid & 1;
  const int kz = blockIdx.z, Kz = K / nkz, k0 = kz * Kz, nt = Kz >> 6;

  const ushort_t* Ab = A + (long)blockIdx.y * TM * lda + k0;
  const ushort_t* Bb = B + (long)blockIdx.x * TN * ldb + k0;

  const ushort_t* srcA[CA]; ushort_t* ldsA[CA];
  const ushort_t* srcB[CB]; ushort_t* ldsB[CB];
#pragma unroll
  for (int c = 0; c < CA; ++c) {
    int off = c * 4096 + tid * 16;
    int row = off >> 7;
    int scol = ((off & 127) ^ ((row & 7) << 4)) >> 1;
    srcA[c] = Ab + (long)row * lda + scol;
    ldsA[c] = As + c * 2048 + wid * 512;
  }
#pragma unroll
  for (int c = 0; c < CB; ++c) {
    int off = c * 4096 + tid * 16;
    int row = off >> 7;
    int scol = ((off & 127) ^ ((row & 7) << 4)) >> 1;
    srcB[c] = Bb + (long)row * ldb + scol;
    ldsB[c] = Bs + c * 2048 + wid * 512;
  }

  f32x4 acc[WM][WN] = {};

  auto STAGE = [&](int buf, int t) {
#pragma unroll
    for (int c = 0; c < CA; ++c) gload16(srcA[c] + t * 64, ldsA[c] + buf * TM * 64);
#pragma unroll
    for (int c = 0; c < CB; ++c) gload16(srcB[c] + t * 64, ldsB[c] + buf * TN * 64);
  };

  STAGE(0, 0);
  STAGE(1, 1);
  for (int t = 0; t < nt; ++t) {
    if (t < nt - 1) { if constexpr (SN == 6) VWAIT(6); else VWAIT(4); }
    else VWAIT(0);
    bar();
    if (t + 2 < nt) STAGE((t + 2) % 3, t + 2);
    const int buf = t % 3;
#pragma unroll
    for (int ks = 0; ks < 2; ++ks) {
      const int kb = ks * 64 + ((lane >> 4) << 4);
      bf16x8 af[WM], bfr[WN];
#pragma unroll
      for (int f = 0; f < WM; ++f) {
        int ra = wm * (TM / 2) + f * 16 + (lane & 15);
        af[f] = *(const bf16x8*)((const char*)As + buf * TM * 128 + ra * 128 + (kb ^ ((ra & 7) << 4)));
      }
#pragma unroll
      for (int g = 0; g < WN; ++g) {
        int rb = wn * (TN / 2) + g * 16 + (lane & 15);
        bfr[g] = *(const bf16x8*)((const char*)Bs + buf * TN * 128 + rb * 128 + (kb ^ ((rb & 7) << 4)));
      }
      __builtin_amdgcn_s_setprio(1);
#pragma unroll
      for (int i = 0; i < WM; ++i)
#pragma unroll
        for (int j = 0; j < WN; ++j)
          acc[i][j] = __builtin_amdgcn_mfma_f32_16x16x32_bf16(af[i], bfr[j], acc[i][j], 0, 0, 0);
      __builtin_amdgcn_s_setprio(0);
    }
  }

  const int row0 = blockIdx.y * TM + wm * (TM / 2) + ((lane >> 4) << 2);
  int col0 = blockIdx.x * TN + wn * (TN / 2) + (lane & 15);
  const float* bsel = bias;
  ushort_t* osel = outB;
  int seg = 0;
  if (EPI == 3) {
    seg = (blockIdx.x * TN) >> 11;
    if (seg == 1) { bsel = bias2; osel = outB2; }
    else if (seg == 2) { bsel = bias3; }
    col0 -= seg * 2048;
  }

  if (EPI == 3 && seg == 2) {
    // V segment: repack 128(row) x 64(col) tile via LDS, write vT[bh][dk][s]
    ushort_t* Vt = As;              // reuse staging LDS (padded stride 136)
    bar();                          // all waves done reading As
#pragma unroll
    for (int i = 0; i < WM; ++i)
#pragma unroll
      for (int j = 0; j < WN; ++j) {
        const int colL = wn * (TN / 2) + j * 16 + (lane & 15);
        const float bv = bsel[(col0 + j * 16) & 2047];
#pragma unroll
        for (int r = 0; r < 4; ++r) {
          const int rowL = wm * (TM / 2) + i * 16 + ((lane >> 4) << 2) + r;
          Vt[colL * 136 + rowL] = f2b(acc[i][j][r] + bv);
        }
      }
    bar();
    const int colvBase = blockIdx.x * TN - 4096;         // within V's 2048 cols
    const int h = colvBase >> 8, dk0 = colvBase & 255;
    const int rowBase = blockIdx.y * TM;
    const int bh = ((rowBase >> 8) << 3) + h;
    const int s0 = rowBase & 255;
    const int dkl = tid >> 2, scc = (tid & 3) * 32;
    ushort_t* dst = outB3 + ((long)bh << 16) + (long)(dk0 + dkl) * 256 + s0 + scc;
#pragma unroll
    for (int m = 0; m < 4; ++m)
      *(u16x8*)(dst + m * 8) = *(const u16x8*)(Vt + dkl * 136 + scc + m * 8);
    return;
  }

#pragma unroll
  for (int i = 0; i < WM; ++i) {
#pragma unroll
    for (int j = 0; j < WN; ++j) {
      const int col = col0 + j * 16;
      float bv;
      if (EPI == 2) bv = (kz == 0) ? bias[col] : 0.f;
      else          bv = bsel[col];
#pragma unroll
      for (int r = 0; r < 4; ++r) {
        const int row = row0 + i * 16 + r;
        float v = acc[i][j][r] + bv;
        if (EPI == 2) {
          outF[(long)kz * 1048576 + (long)row * ldc + col] = v;
        } else if (EPI == 3) {
          // head-major: [bh][s][dk]
          const long addr = (((long)(row >> 8) * 8 + (col >> 8)) << 16) +
                            (long)(row & 255) * 256 + (col & 255);
          osel[addr] = f2b(v);
        } else {
          if (relu) v = fmaxf(v, 0.f);
          osel[(long)row * ldc + col] = f2b(v);
        }
      }
    }
  }
}

// ---------------------------------------------------------------------------
// Attention: one wave per (16-row q-tile, head), XCD-mapped. All operands
// head-major contiguous; staged via global_load_lds (contiguous 1KB/instr,
// source granule-swizzled), 3-buffer depth-2 rotation, counted vmcnt(8),
// zero barriers. Q frags hoisted to regs; P/O repack through 8KB LDS.
// ---------------------------------------------------------------------------
__global__ __launch_bounds__(64, 1)
void attn_k(const ushort_t* __restrict__ qh, const ushort_t* __restrict__ kh,
            const ushort_t* __restrict__ vT, const int* __restrict__ attnm,
            ushort_t* __restrict__ ao)
{
  __shared__ ushort_t QP[16 * 256];      // 8KB: Q tile -> P -> O repack
  __shared__ ushort_t KV[3][16 * 256];   // 24KB rotating K/V chunk buffers
  __shared__ int Ml[256];                // 1KB mask row
  const int i = blockIdx.x;
  const int xcd = i & 7, slot = i >> 3;
  const int bh = xcd + 8 * (slot >> 4);  // all 16 q-tiles of bh on one XCD
  const int qt = slot & 15;
  const int b = bh >> 3, h = bh & 7;
  const int lane = threadIdx.x;
  const int l15 = lane & 15, l4 = lane >> 4;
  const int q0 = qt * 16;

  // per-lane source offsets (elements) for a 16x256 chunk, granule-swizzled
  int soff[8];
#pragma unroll
  for (int c = 0; c < 8; ++c) {
    int r = 2 * c + (lane >> 5);
    int cb = ((lane & 31) * 16) ^ ((r & 7) << 4);
    soff[c] = r * 256 + (cb >> 1);
  }
  const ushort_t* Qg = qh + ((long)bh << 16) + q0 * 256;
  const ushort_t* Kg = kh + ((long)bh << 16);
  const ushort_t* Vg = vT + ((long)bh << 16);

#define STG(SRC, DSTBUF) do { _Pragma("unroll") for (int c = 0; c < 8; ++c) \
    gload16((SRC) + soff[c], (DSTBUF) + c * 512); } while (0)

  // prologue: Q(8), mask(1), K0(8), K1(8) in flight
  STG(Qg, QP);
  gload16(attnm + b * 256 + lane * 4, Ml);
  STG(Kg + 0 * 4096, KV[0]);
  STG(Kg + 1 * 4096, KV[1]);

  VWAIT(8);                         // Q, mask, K0 landed
  bf16x8 qf[8];
#pragma unroll
  for (int ks = 0; ks < 8; ++ks)
    qf[ks] = *(const bf16x8*)((const char*)QP + l15 * 512 + ((ks * 64 + l4 * 16) ^ ((l15 & 7) << 4)));

  // S = Q K^T : 16 chunks of 16 keys, depth-2 prefetch
  f32x4 sacc[16] = {};
#pragma unroll
  for (int kt = 0; kt < 16; ++kt) {
    if (kt) VWAIT(8);
    if (kt < 14) STG(Kg + (kt + 2) * 4096, KV[(kt + 2) % 3]);
    else         STG(Vg + (kt - 14) * 4096, KV[(kt + 2) % 3]);
    const char* kb = (const char*)KV[kt % 3];
#pragma unroll
    for (int ks = 0; ks < 8; ++ks) {
      bf16x8 kf = *(const bf16x8*)(kb + l15 * 512 + ((ks * 64 + l4 * 16) ^ ((l15 & 7) << 4)));
      sacc[kt] = __builtin_amdgcn_mfma_f32_16x16x32_bf16(qf[ks], kf, sacc[kt], 0, 0, 0);
    }
  }

  // softmax over 256 keys; lane holds keys kt*16+l15 for q-rows l4*4+r
  float mr[4] = {-3e38f, -3e38f, -3e38f, -3e38f}, sr[4] = {};
#pragma unroll
  for (int kt = 0; kt < 16; ++kt) {
    const bool mk = Ml[kt * 16 + l15] != 0;
#pragma unroll
    for (int r = 0; r < 4; ++r) {
      float s = mk ? -1e9f : sacc[kt][r] * 0.0625f;
      sacc[kt][r] = s;
      mr[r] = fmaxf(mr[r], s);
    }
  }
#pragma unroll
  for (int o = 1; o < 16; o <<= 1)
#pragma unroll
    for (int r = 0; r < 4; ++r) mr[r] = fmaxf(mr[r], __shfl_xor(mr[r], o, 16));
#pragma unroll
  for (int kt = 0; kt < 16; ++kt)
#pragma unroll
    for (int r = 0; r < 4; ++r) {
      float e = __expf(sacc[kt][r] - mr[r]);
      sacc[kt][r] = e;
      sr[r] += e;
    }
#pragma unroll
  for (int o = 1; o < 16; o <<= 1)
#pragma unroll
    for (int r = 0; r < 4; ++r) sr[r] += __shfl_xor(sr[r], o, 16);
#pragma unroll
  for (int r = 0; r < 4; ++r) sr[r] = 1.f / sr[r];

  // P -> QP (Q dead), swizzled
#pragma unroll
  for (int kt = 0; kt < 16; ++kt)
#pragma unroll
    for (int r = 0; r < 4; ++r) {
      const int row = l4 * 4 + r;
      *(ushort_t*)((char*)QP + row * 512 + (((kt * 16 + l15) * 2) ^ ((row & 7) << 4))) =
          f2b(sacc[kt][r] * sr[r]);
    }
  bf16x8 pf[8];
#pragma unroll
  for (int ks = 0; ks < 8; ++ks)
    pf[ks] = *(const bf16x8*)((const char*)QP + l15 * 512 + ((ks * 64 + l4 * 16) ^ ((l15 & 7) << 4)));

  // O = P V : 16 chunks of 16 dk-rows, depth-2 prefetch
  f32x4 oacc[16] = {};
#pragma unroll
  for (int dt = 0; dt < 16; ++dt) {
    if (dt < 14)      { VWAIT(8); STG(Vg + (dt + 2) * 4096, KV[(dt + 18) % 3]); }
    else if (dt == 14) VWAIT(8);
    else               VWAIT(0);
    const char* vb = (const char*)KV[(dt + 16) % 3];
#pragma unroll
    for (int ks = 0; ks < 8; ++ks) {
      bf16x8 vf = *(const bf16x8*)(vb + l15 * 512 + ((ks * 64 + l4 * 16) ^ ((l15 & 7) << 4)));
      oacc[dt] = __builtin_amdgcn_mfma_f32_16x16x32_bf16(pf[ks], vf, oacc[dt], 0, 0, 0);
    }
  }

  // O -> QP (swizzled) -> coalesced 16B stores to ao [b,s,h*dk]
#pragma unroll
  for (int dt = 0; dt < 16; ++dt)
#pragma unroll
    for (int r = 0; r < 4; ++r) {
      const int row = l4 * 4 + r;
      *(ushort_t*)((char*)QP + row * 512 + (((dt * 16 + l15) * 2) ^ ((row & 7) << 4))) =
          f2b(oacc[dt][r]);
    }
  ushort_t* dst = ao + (long)(b * 256 + q0 + l15) * 2048 + h * 256 + l4 * 64;
#pragma unroll
  for (int m = 0; m < 8; ++m) {
    const int cbyte = l4 * 128 + m * 16;
    u16x8 v = *(const u16x8*)((const char*)QP + l15 * 512 + (cbyte ^ ((l15 & 7) << 4)));
    *(u16x8*)(dst + m * 8) = v;
  }
#undef STG
}

// x = data*sqrt(D) + pe + seg_emb[view_idx*S]
__global__ __launch_bounds__(256)
void build_x(const float* __restrict__ data, const float* __restrict__ seg,
             const int* __restrict__ viewp, float* __restrict__ x)
{
  int i = blockIdx.x * 256 + threadIdx.x;
  int d = i & 511;
  int s = (i >> 9) & 255;
  float ang = (float)s * exp2f((float)d * -0.03125f);
  float pe = (d & 1) ? cosf(ang) : sinf(ang);
  int vrow = viewp[0] * SS;
  x[i] = data[i] * 22.627416997969522f + pe + seg[vrow * DIM + d];
}

// LayerNorm with optional fused residual: x += sum(parts[0..np)), write back,
// then normalize (unbiased var, eps on std). outB: bf16 out; outF: fp32 out.
__global__ __launch_bounds__(256)
void lnorm_k(const float* __restrict__ x, const float* __restrict__ parts, int np,
             float* __restrict__ xout,
             const float* __restrict__ alpha, const float* __restrict__ beta,
             ushort_t* __restrict__ outB, float* __restrict__ outF)
{
  const int row = blockIdx.x, tid = threadIdx.x;
  const long base = (long)row * DIM;
  float2 v = ((const float2*)(x + base))[tid];
  if (np) {
    for (int p = 0; p < np; ++p) {
      float2 a = ((const float2*)(parts + (long)p * 1048576 + base))[tid];
      v.x += a.x; v.y += a.y;
    }
    ((float2*)(xout + base))[tid] = v;
  }
  float s = v.x + v.y;
#pragma unroll
  for (int o = 32; o; o >>= 1) s += __shfl_xor(s, o, 64);
  __shared__ float rs[4], rq[4];
  if ((tid & 63) == 0) rs[tid >> 6] = s;
  __syncthreads();
  const float mu = (rs[0] + rs[1] + rs[2] + rs[3]) * (1.f / 512.f);
  const float dx = v.x - mu, dy = v.y - mu;
  float q = dx * dx + dy * dy;
#pragma unroll
  for (int o = 32; o; o >>= 1) q += __shfl_xor(q, o, 64);
  if ((tid & 63) == 0) rq[tid >> 6] = q;
  __syncthreads();
  const float var = (rq[0] + rq[1] + rq[2] + rq[3]) * (1.f / 511.f);
  const float rstd = 1.f / (sqrtf(var) + 1e-6f);
  const int d0 = tid * 2;
  const float o0 = alpha[d0] * dx * rstd + beta[d0];
  const float o1 = alpha[d0 + 1] * dy * rstd + beta[d0 + 1];
  if (outB) { outB[base + d0] = f2b(o0); outB[base + d0 + 1] = f2b(o1); }
  else      { outF[base + d0] = o0;      outF[base + d0 + 1] = o1; }
}

// fp32 [R,C] -> bf16 [C,R], per-z with output z-stride (elements)
__global__ __launch_bounds__(256)
void wtrans(const float* __restrict__ in, ushort_t* __restrict__ out,
            int R, int C, long ozs)
{
  __shared__ float t[32][33];
  const int z = blockIdx.z;
  const long zi = (long)z * R * C, zo = (long)z * ozs;
  const int c0 = blockIdx.x * 32, r0 = blockIdx.y * 32;
  const int tx = threadIdx.x & 31, ty = threadIdx.x >> 5;
#pragma unroll
  for (int i = 0; i < 4; ++i) t[ty + i * 8][tx] = in[zi + (long)(r0 + ty + i * 8) * C + c0 + tx];
  __syncthreads();
#pragma unroll
  for (int i = 0; i < 4; ++i) out[zo + (long)(c0 + ty + i * 8) * R + r0 + tx] = f2b(t[tx][ty + i * 8]);
}

extern "C" void kernel_launch(void* const* d_in, const int* in_sizes, int n_in,
                              void* d_out, int out_size, void* d_ws, size_t ws_size,
                              hipStream_t stream)
{
  const float* data  = (const float*)d_in[0];
  const int*   attnm = (const int*)d_in[1];
  const int*   viewp = (const int*)d_in[2];
  const float* seg   = (const float*)d_in[3];
  const float* Wq    = (const float*)d_in[4];
  const float* bq    = (const float*)d_in[5];
  const float* Wk    = (const float*)d_in[6];
  const float* bk    = (const float*)d_in[7];
  const float* Wv    = (const float*)d_in[8];
  const float* bv    = (const float*)d_in[9];
  const float* Wo    = (const float*)d_in[10];
  const float* bo    = (const float*)d_in[11];
  const float* W1    = (const float*)d_in[12];
  const float* b1    = (const float*)d_in[13];
  const float* W2    = (const float*)d_in[14];
  const float* b2    = (const float*)d_in[15];
  const float* al1   = (const float*)d_in[16];
  const float* be1   = (const float*)d_in[17];
  const float* al2   = (const float*)d_in[18];
  const float* be2   = (const float*)d_in[19];
  const float* alf   = (const float*)d_in[20];
  const float* bef   = (const float*)d_in[21];

  char* w = (char*)d_ws;
  const size_t MB = 1024 * 1024;
  ushort_t* qkvW = (ushort_t*)(w + 0 * MB);   // [L][6144][512] bf16
  ushort_t* WoT  = (ushort_t*)(w + 24 * MB);  // [L][512][2048]
  ushort_t* W1T  = (ushort_t*)(w + 32 * MB);  // [L][2048][512]
  ushort_t* W2T  = (ushort_t*)(w + 40 * MB);  // [L][512][2048]
  float*    x    = (float*)   (w + 48 * MB);  // [2048][512] fp32
  ushort_t* x2   = (ushort_t*)(w + 52 * MB);  // [2048][512] bf16
  ushort_t* qb   = (ushort_t*)(w + 54 * MB);  // [64][256][256] bf16 head-major Q
  ushort_t* kbf  = (ushort_t*)(w + 62 * MB);  // [64][256][256] bf16 head-major K
  ushort_t* vT   = (ushort_t*)(w + 70 * MB);  // [64][256][256] V^T
  ushort_t* ao   = (ushort_t*)(w + 78 * MB);  // [2048][2048]
  ushort_t* ffh  = (ushort_t*)(w + 86 * MB);  // [2048][2048]
  float*    parts= (float*)   (w + 94 * MB);  // 4 x [2048][512] fp32 (94..110MB)

  dim3 blk(256);
  const long QKV_L = 6144L * 512;
  wtrans<<<dim3(64, 16, 4), blk, 0, stream>>>(Wq, qkvW + 0 * 2048 * 512, 512, 2048, QKV_L);
  wtrans<<<dim3(64, 16, 4), blk, 0, stream>>>(Wk, qkvW + 1 * 2048 * 512, 512, 2048, QKV_L);
  wtrans<<<dim3(64, 16, 4), blk, 0, stream>>>(Wv, qkvW + 2 * 2048 * 512, 512, 2048, QKV_L);
  wtrans<<<dim3(16, 64, 4), blk, 0, stream>>>(Wo, WoT, 2048, 512, 512L * 2048);
  wtrans<<<dim3(64, 16, 4), blk, 0, stream>>>(W1, W1T, 512, 2048, 2048L * 512);
  wtrans<<<dim3(16, 64, 4), blk, 0, stream>>>(W2, W2T, 2048, 512, 512L * 2048);
  build_x<<<4096, blk, 0, stream>>>(data, seg, viewp, x);

  for (int i = 0; i < LNUM; ++i) {
    if (i == 0)
      lnorm_k<<<2048, blk, 0, stream>>>(x, nullptr, 0, nullptr, al1, be1, x2, nullptr);
    // fused QKV: [2048,512] x [6144,512]^T ; Q,K head-major; V repacked to vT
    gemm_bt<128, 64, 3><<<dim3(96, 16, 1), blk, 0, stream>>>(
        x2, qkvW + (long)i * QKV_L, bq + i * 2048, bk + i * 2048, bv + i * 2048,
        qb, kbf, vT, nullptr, 512, 512, 512, 2048, 1, 0);
    attn_k<<<dim3(1024), dim3(64), 0, stream>>>(qb, kbf, vT, attnm, ao);
    // Wo: [2048,2048] x [512,2048]^T, split-K=4 -> parts
    gemm_bt<64, 64, 2><<<dim3(8, 32, 4), blk, 0, stream>>>(
        ao, WoT + (long)i * 512 * 2048, bo + i * 512, nullptr, nullptr,
        nullptr, nullptr, nullptr, parts, 2048, 2048, 2048, 512, 4, 0);
    lnorm_k<<<2048, blk, 0, stream>>>(x, parts, 4, x, al2 + i * 512, be2 + i * 512, x2, nullptr);
    // FF1: [2048,512] x [2048,512]^T, relu
    gemm_bt<128, 64, 0><<<dim3(32, 16, 1), blk, 0, stream>>>(
        x2, W1T + (long)i * 2048 * 512, b1 + i * 2048, nullptr, nullptr,
        ffh, nullptr, nullptr, nullptr, 512, 512, 512, 2048, 1, 1);
    // FF2: [2048,2048] x [512,2048]^T, split-K=4 -> parts
    gemm_bt<64, 64, 2><<<dim3(8, 32, 4), blk, 0, stream>>>(
        ffh, W2T + (long)i * 512 * 2048, b2 + i * 512, nullptr, nullptr,
        nullptr, nullptr, nullptr, parts, 2048, 2048, 2048, 512, 4, 0);
    if (i < LNUM - 1)
      lnorm_k<<<2048, blk, 0, stream>>>(x, parts, 4, x, al1 + (i + 1) * 512, be1 + (i + 1) * 512, x2, nullptr);
    else
      lnorm_k<<<2048, blk, 0, stream>>>(x, parts, 4, x, alf, bef, nullptr, (float*)d_out);
  }
}